// Round 1
// baseline (68.120 us; speedup 1.0000x reference)
//
#include <hip/hip_runtime.h>
#include <math.h>

// ---------------------------------------------------------------------------
// RISVQCLayer: angles = tanh(fused @ W^T + b) * pi  -> 4-qubit VQC -> (z+1)*pi
// B=65536, HID=256, R=16 runs of 4 qubits (64 outputs per sample), all fp32.
//
// Layout: block = 1024 threads = 16 waves. Wave w handles r=w (wave-uniform,
// so W_proj/b_proj/weight-sincos loads become scalar s_loads). lane = local
// batch row. Block tiles 64 batch rows; fused tile staged in LDS stride 257
// (conflict-free reads). Circuit state = 16 floats in registers; CNOTs are
// compile-time permutations (zero instructions).
// ---------------------------------------------------------------------------

#define PI_F 3.14159265358979323846f

__device__ __forceinline__ void ry_gate(float st[16], float c, float s, int w) {
    const int m = 1 << (3 - w);
    #pragma unroll
    for (int i = 0; i < 16; ++i) {
        if (i & m) continue;
        float a = st[i];
        float b = st[i | m];
        st[i]     = c * a - s * b;
        st[i | m] = s * a + c * b;
    }
}

__device__ __forceinline__ void cnot_gate(float st[16], int cw, int tw) {
    const int cm = 1 << (3 - cw);
    const int tm = 1 << (3 - tw);
    #pragma unroll
    for (int i = 0; i < 16; ++i) {
        if ((i & cm) && !(i & tm)) {
            float tmp = st[i];
            st[i] = st[i | tm];
            st[i | tm] = tmp;
        }
    }
}

// apply one variational layer's 4 RY gates; wcs points at 8 floats:
// (cos,sin) pairs for wires 0..3
__device__ __forceinline__ void ry_layer(float st[16], const float* __restrict__ wcs) {
    #pragma unroll
    for (int w = 0; w < 4; ++w) {
        ry_gate(st, wcs[2 * w], wcs[2 * w + 1], w);
    }
}

// Precompute cos/sin of half-angles of the 256 variational weights.
// vw: (R=16, 4 layers, 4 wires); ws: 512 floats, [(r*16 + l*4 + w)*2 + {c,s}]
__global__ void prep_weights_kernel(const float* __restrict__ vw,
                                    float* __restrict__ ws) {
    int i = threadIdx.x;
    if (i < 256) {
        float h = vw[i] * 0.5f;
        ws[2 * i]     = __cosf(h);
        ws[2 * i + 1] = __sinf(h);
    }
}

__global__ __launch_bounds__(1024) void vqc_main_kernel(
        const float* __restrict__ fused,   // (65536, 256)
        const float* __restrict__ W,       // (64, 256)
        const float* __restrict__ bp,      // (64,)
        const float* __restrict__ wcs,     // (16, 32) precomputed cos/sin
        float* __restrict__ out) {         // (65536, 64)
    __shared__ float lds[64 * 257];

    const int tid = threadIdx.x;
    const int b0  = blockIdx.x * 64;

    // ---- stage fused tile (64 rows x 256 cols) into LDS, stride 257 ----
    {
        const float4* src = (const float4*)(fused + (size_t)b0 * 256);
        #pragma unroll
        for (int it = 0; it < 4; ++it) {
            int q = tid + it * 1024;          // float4 index, 4096 total
            float4 v = src[q];
            int row = q >> 6;
            int c4  = (q & 63) << 2;
            float* d = &lds[row * 257 + c4];
            d[0] = v.x; d[1] = v.y; d[2] = v.z; d[3] = v.w;
        }
    }
    __syncthreads();

    const int lane = tid & 63;                                  // local batch row
    const int r    = __builtin_amdgcn_readfirstlane(tid >> 6);  // wave-uniform run id

    // ---- 4 dot products: angles pre-activation ----
    const float* Wr = W + (size_t)r * 4 * 256;   // uniform -> s_load
    float acc0 = bp[4 * r + 0];
    float acc1 = bp[4 * r + 1];
    float acc2 = bp[4 * r + 2];
    float acc3 = bp[4 * r + 3];
    const float* arow = &lds[lane * 257];
    #pragma unroll 8
    for (int k = 0; k < 256; ++k) {
        float a = arow[k];
        acc0 = fmaf(a, Wr[k],       acc0);
        acc1 = fmaf(a, Wr[256 + k], acc1);
        acc2 = fmaf(a, Wr[512 + k], acc2);
        acc3 = fmaf(a, Wr[768 + k], acc3);
    }

    // ---- encoding angles: theta = tanh(pre)*pi; need sincos(theta/2) ----
    float pre[4] = {acc0, acc1, acc2, acc3};
    float c[4], s[4];
    #pragma unroll
    for (int w = 0; w < 4; ++w) {
        float e  = __expf(2.f * pre[w]);
        float th = 1.f - 2.f / (e + 1.f);          // tanh(pre)
        float h  = th * (0.5f * PI_F);             // theta/2
        __sincosf(h, &s[w], &c[w]);
    }

    // ---- initial state after encoding layer: product state ----
    // st[i] = f0(b0)*f1(b1)*f2(b2)*f3(b3), bw = bit (3-w) of i, f(0)=c,f(1)=s
    float st[16];
    {
        float a01[4] = {c[0] * c[1], c[0] * s[1], s[0] * c[1], s[0] * s[1]};
        float a23[4] = {c[2] * c[3], c[2] * s[3], s[2] * c[3], s[2] * s[3]};
        #pragma unroll
        for (int hi = 0; hi < 4; ++hi)
            #pragma unroll
            for (int lo = 0; lo < 4; ++lo)
                st[hi * 4 + lo] = a01[hi] * a23[lo];
    }

    // ---- variational layers (weight sincos are wave-uniform s_loads) ----
    const float* wr = wcs + r * 32;
    ry_layer(st, wr + 0);                 // layer 0
    cnot_gate(st, 0, 1);
    cnot_gate(st, 2, 3);
    ry_layer(st, wr + 8);                 // layer 1
    cnot_gate(st, 1, 2);
    cnot_gate(st, 3, 0);
    ry_layer(st, wr + 16);                // layer 2
    cnot_gate(st, 0, 1);
    cnot_gate(st, 1, 2);
    cnot_gate(st, 2, 3);
    cnot_gate(st, 3, 0);
    ry_layer(st, wr + 24);                // layer 3

    // ---- Z expectations and output ----
    float z[4] = {0.f, 0.f, 0.f, 0.f};
    #pragma unroll
    for (int i = 0; i < 16; ++i) {
        float p = st[i] * st[i];
        #pragma unroll
        for (int w = 0; w < 4; ++w) {
            if ((i >> (3 - w)) & 1) z[w] -= p; else z[w] += p;
        }
    }

    float4 o;
    o.x = (z[0] + 1.f) * PI_F;
    o.y = (z[1] + 1.f) * PI_F;
    o.z = (z[2] + 1.f) * PI_F;
    o.w = (z[3] + 1.f) * PI_F;
    *(float4*)(out + (size_t)(b0 + lane) * 64 + r * 4) = o;
}

extern "C" void kernel_launch(void* const* d_in, const int* in_sizes, int n_in,
                              void* d_out, int out_size, void* d_ws, size_t ws_size,
                              hipStream_t stream) {
    const float* fused = (const float*)d_in[0];   // (65536, 256)
    const float* Wp    = (const float*)d_in[1];   // (64, 256)
    const float* bp    = (const float*)d_in[2];   // (64,)
    const float* vw    = (const float*)d_in[3];   // (16, 4, 4)
    float* out = (float*)d_out;                   // (65536, 64)
    float* wcs = (float*)d_ws;                    // 512 floats scratch

    prep_weights_kernel<<<1, 256, 0, stream>>>(vw, wcs);

    const int B = 65536;
    vqc_main_kernel<<<B / 64, 1024, 0, stream>>>(fused, Wp, bp, wcs, out);
}

// Round 3
// 44.021 us; speedup vs baseline: 1.5474x; 1.5474x over previous
//
#include <hip/hip_runtime.h>
#include <math.h>

// ---------------------------------------------------------------------------
// RISVQCLayer: angles = tanh(fused @ W^T + b) * pi  -> 4-qubit VQC -> (z+1)*pi
// B=65536, HID=256, R=16 runs (64 outputs/sample), fp32 in/out.
//
// R2: transposed MFMA GEMM (pre^T = W · fused^T) so each lane's 4 accumulator
// regs ARE the 4 angles of one run for one sample — no C park/reload, no LDS
// aliasing. Block=256thr/4 waves; wave sg owns samples sg*16..+15; acc[cg]
// covers runs r=cg*4+(lane>>4). W + fused tiles staged fp16 in LDS (32KB+32KB)
// with XOR-swizzled 16B slots (transparent relabel; conflict-free b128 reads).
// Weight sincos staged as float2 in LDS, stride 17 (bank-spread broadcast).
// ---------------------------------------------------------------------------

#define PI_F 3.14159265358979323846f

typedef _Float16 f16x4 __attribute__((ext_vector_type(4)));
typedef _Float16 f16x8 __attribute__((ext_vector_type(8)));
typedef float    f32x4 __attribute__((ext_vector_type(4)));

__device__ __forceinline__ void ry_gate(float st[16], float c, float s, int w) {
    const int m = 1 << (3 - w);
    #pragma unroll
    for (int i = 0; i < 16; ++i) {
        if (i & m) continue;
        float a = st[i];
        float b = st[i | m];
        st[i]     = c * a - s * b;
        st[i | m] = s * a + c * b;
    }
}

__device__ __forceinline__ void cnot_gate(float st[16], int cw, int tw) {
    const int cm = 1 << (3 - cw);
    const int tm = 1 << (3 - tw);
    #pragma unroll
    for (int i = 0; i < 16; ++i) {
        if ((i & cm) && !(i & tm)) {
            float tmp = st[i];
            st[i] = st[i | tm];
            st[i | tm] = tmp;
        }
    }
}

__device__ __forceinline__ void ry_layer2(float st[16], const float2* __restrict__ p) {
    #pragma unroll
    for (int w = 0; w < 4; ++w) {
        ry_gate(st, p[w].x, p[w].y, w);
    }
}

// Precompute (cos,sin) of half-angles of the 256 variational weights.
// vw: (R=16, 4 layers, 4 wires) row-major; ws[i] pairs, i = r*16 + l*4 + w.
__global__ void prep_weights_kernel(const float* __restrict__ vw,
                                    float2* __restrict__ ws) {
    int i = threadIdx.x;
    if (i < 256) {
        float h = vw[i] * 0.5f;
        ws[i] = make_float2(__cosf(h), __sinf(h));
    }
}

// Stage a 64x256 fp32 tile as fp16 into LDS with 16B-slot XOR swizzle.
// byte addr = row*512 + ((slot ^ (row&7))*16 + (k&7)*2), slot = k>>3.
__device__ __forceinline__ void stage_tile(const float* __restrict__ src,
                                           char* dst, int tid) {
    const float4* s4 = (const float4*)src;
    #pragma unroll
    for (int it = 0; it < 16; ++it) {
        int q = tid + it * 256;            // float4 index, 4096 total
        float4 v = s4[q];
        int row = q >> 6;
        int c4  = (q & 63) << 2;           // k, multiple of 4
        int sl  = (c4 >> 3) ^ (row & 7);
        int byteoff = row * 512 + (sl << 4) + ((c4 & 7) << 1);
        f16x4 h = { (_Float16)v.x, (_Float16)v.y, (_Float16)v.z, (_Float16)v.w };
        *(f16x4*)(dst + byteoff) = h;
    }
}

__global__ __launch_bounds__(256) void vqc_main_kernel(
        const float* __restrict__ fused,   // (65536, 256)
        const float* __restrict__ W,       // (64, 256)
        const float* __restrict__ bp,      // (64,)
        const float2* __restrict__ wcs,    // 256 (cos,sin) pairs
        float* __restrict__ out) {         // (65536, 64)
    __shared__ __align__(16) char smem[65536 + 2304];
    char*   Wl   = smem;                   // fp16 [64][256] swizzled, 32 KB
    char*   Al   = smem + 32768;           // fp16 [64][256] swizzled, 32 KB
    float2* wcsl = (float2*)(smem + 65536);// [16][17] padded (cos,sin)

    const int tid = threadIdx.x;
    const int b0  = blockIdx.x * 64;

    stage_tile(W, Wl, tid);
    stage_tile(fused + (size_t)b0 * 256, Al, tid);
    {   // stage weight sincos with stride-17 padding
        int r = tid >> 4, idx = tid & 15;
        wcsl[r * 17 + idx] = wcs[tid];
    }
    __syncthreads();

    const int lane = tid & 63;
    const int sg   = tid >> 6;             // wave id = sample sub-group
    const int l15  = lane & 15;
    const int l4   = lane >> 4;
    const int frow = sg * 16 + l15;        // sample row within tile (B operand)

    // ---- MFMA: D = W-rows (A) x fused-rows (B) -> pre^T fragments ----
    f32x4 acc[4] = {};
    #pragma unroll
    for (int kk = 0; kk < 8; ++kk) {
        int slot = kk * 4 + l4;            // 16B slot index within a row
        f16x8 bf = *(const f16x8*)(Al + frow * 512 + ((slot ^ (frow & 7)) << 4));
        #pragma unroll
        for (int cg = 0; cg < 4; ++cg) {
            int wrow = cg * 16 + l15;      // W row = angle column
            f16x8 af = *(const f16x8*)(Wl + wrow * 512 + ((slot ^ (wrow & 7)) << 4));
            acc[cg] = __builtin_amdgcn_mfma_f32_16x16x32_f16(af, bf, acc[cg], 0, 0, 0);
        }
    }

    // ---- epilogue: acc[cg][j] = pre[b0+frow][4*(cg*4+l4)+j] ----
    #pragma unroll
    for (int cg = 0; cg < 4; ++cg) {
        const int r = cg * 4 + l4;
        float4 bpv = *(const float4*)(bp + 4 * r);
        float pre[4] = { acc[cg][0] + bpv.x, acc[cg][1] + bpv.y,
                         acc[cg][2] + bpv.z, acc[cg][3] + bpv.w };

        float cc[4], ss[4];
        #pragma unroll
        for (int w = 0; w < 4; ++w) {
            float e  = __expf(2.f * pre[w]);
            float th = 1.f - 2.f / (e + 1.f);      // tanh(pre)
            float h  = th * (0.5f * PI_F);         // theta/2
            __sincosf(h, &ss[w], &cc[w]);
        }

        // product state after encoding layer
        float st[16];
        {
            float a01[4] = {cc[0]*cc[1], cc[0]*ss[1], ss[0]*cc[1], ss[0]*ss[1]};
            float a23[4] = {cc[2]*cc[3], cc[2]*ss[3], ss[2]*cc[3], ss[2]*ss[3]};
            #pragma unroll
            for (int hi = 0; hi < 4; ++hi)
                #pragma unroll
                for (int lo = 0; lo < 4; ++lo)
                    st[hi * 4 + lo] = a01[hi] * a23[lo];
        }

        const float2* wr = wcsl + r * 17;  // LDS broadcast, bank-spread
        ry_layer2(st, wr + 0);             // layer 0
        cnot_gate(st, 0, 1);
        cnot_gate(st, 2, 3);
        ry_layer2(st, wr + 4);             // layer 1
        cnot_gate(st, 1, 2);
        cnot_gate(st, 3, 0);
        ry_layer2(st, wr + 8);             // layer 2
        cnot_gate(st, 0, 1);
        cnot_gate(st, 1, 2);
        cnot_gate(st, 2, 3);
        cnot_gate(st, 3, 0);
        ry_layer2(st, wr + 12);            // layer 3

        float z[4] = {0.f, 0.f, 0.f, 0.f};
        #pragma unroll
        for (int i = 0; i < 16; ++i) {
            float p = st[i] * st[i];
            #pragma unroll
            for (int w = 0; w < 4; ++w) {
                if ((i >> (3 - w)) & 1) z[w] -= p; else z[w] += p;
            }
        }

        float4 o;
        o.x = (z[0] + 1.f) * PI_F;
        o.y = (z[1] + 1.f) * PI_F;
        o.z = (z[2] + 1.f) * PI_F;
        o.w = (z[3] + 1.f) * PI_F;
        *(float4*)(out + (size_t)(b0 + frow) * 64 + 4 * r) = o;
    }
}

extern "C" void kernel_launch(void* const* d_in, const int* in_sizes, int n_in,
                              void* d_out, int out_size, void* d_ws, size_t ws_size,
                              hipStream_t stream) {
    const float* fused = (const float*)d_in[0];   // (65536, 256)
    const float* Wp    = (const float*)d_in[1];   // (64, 256)
    const float* bp    = (const float*)d_in[2];   // (64,)
    const float* vw    = (const float*)d_in[3];   // (16, 4, 4)
    float* out = (float*)d_out;                   // (65536, 64)
    float2* wcs = (float2*)d_ws;                  // 256 float2 scratch

    prep_weights_kernel<<<1, 256, 0, stream>>>(vw, wcs);

    const int B = 65536;
    vqc_main_kernel<<<B / 64, 256, 0, stream>>>(fused, Wp, bp, wcs, out);
}

// Round 4
// 36.269 us; speedup vs baseline: 1.8782x; 1.2137x over previous
//
#include <hip/hip_runtime.h>
#include <math.h>

// ---------------------------------------------------------------------------
// RISVQCLayer: angles = tanh(fused @ W^T + b) * pi  -> 4-qubit VQC -> (z+1)*pi
// B=65536, HID=256, R=16 runs (64 outputs/sample), fp32 in/out.
//
// R3 structure:
//  prep (2 blocks): block0 composes U_r = full post-encoding circuit (16x16
//    orthogonal, batch-independent) per run r -> d_ws[32768..]; block1 packs
//    W into MFMA-fragment-ordered fp16 -> d_ws[0..32767].
//  main (1024 blocks, 256 thr): A-tile fp16 XOR-swizzled in LDS (32KB only);
//    W fragments read from global (L1-hot). Transposed MFMA (pre^T = W·A^T,
//    R2-verified layout). pre parked in LDS (aliases dead A buffer, stride
//    66), re-read with wave-uniform r -> U_r + bias are scalar loads. Circuit
//    = s_enc outer product + dense U apply (256 FMA) + tree Z-reduction.
// ---------------------------------------------------------------------------

#define PI_F 3.14159265358979323846f

typedef _Float16 f16x4 __attribute__((ext_vector_type(4)));
typedef _Float16 f16x8 __attribute__((ext_vector_type(8)));
typedef float    f32x4 __attribute__((ext_vector_type(4)));

__device__ __forceinline__ void ry_gate(float st[16], float c, float s, int w) {
    const int m = 1 << (3 - w);
    #pragma unroll
    for (int i = 0; i < 16; ++i) {
        if (i & m) continue;
        float a = st[i];
        float b = st[i | m];
        st[i]     = c * a - s * b;
        st[i | m] = s * a + c * b;
    }
}

__device__ __forceinline__ void cnot_gate(float st[16], int cw, int tw) {
    const int cm = 1 << (3 - cw);
    const int tm = 1 << (3 - tw);
    #pragma unroll
    for (int i = 0; i < 16; ++i) {
        if ((i & cm) && !(i & tm)) {
            float tmp = st[i];
            st[i] = st[i | tm];
            st[i | tm] = tmp;
        }
    }
}

// prep: block 0 -> U matrices (thread (r,j): circuit applied to basis e_j),
//       block 1 -> W repacked as fp16 MFMA fragments.
// d_ws layout: [0, 32768) fp16 W fragments; [32768, 49152) fp32 U[16][16][16].
__global__ void prep_kernel(const float* __restrict__ vw,
                            const float* __restrict__ W,
                            char* __restrict__ ws) {
    const int tid = threadIdx.x;   // 256
    if (blockIdx.x == 0) {
        float* Uws = (float*)(ws + 32768);
        const int r = tid >> 4, j = tid & 15;
        const float* wr = vw + r * 16;       // vw[r][layer][wire]
        float cs[16], sn[16];
        #pragma unroll
        for (int i = 0; i < 16; ++i) {
            float h = wr[i] * 0.5f;
            cs[i] = __cosf(h);
            sn[i] = __sinf(h);
        }
        float st[16];
        #pragma unroll
        for (int i = 0; i < 16; ++i) st[i] = 0.f;
        st[j] = 1.f;
        #pragma unroll
        for (int w = 0; w < 4; ++w) ry_gate(st, cs[w], sn[w], w);       // layer 0
        cnot_gate(st, 0, 1);
        cnot_gate(st, 2, 3);
        #pragma unroll
        for (int w = 0; w < 4; ++w) ry_gate(st, cs[4 + w], sn[4 + w], w); // layer 1
        cnot_gate(st, 1, 2);
        cnot_gate(st, 3, 0);
        #pragma unroll
        for (int w = 0; w < 4; ++w) ry_gate(st, cs[8 + w], sn[8 + w], w); // layer 2
        cnot_gate(st, 0, 1);
        cnot_gate(st, 1, 2);
        cnot_gate(st, 2, 3);
        cnot_gate(st, 3, 0);
        #pragma unroll
        for (int w = 0; w < 4; ++w) ry_gate(st, cs[12 + w], sn[12 + w], w); // layer 3
        // Uws[r][j][i] = U_r[i][j]  (st = U e_j)
        #pragma unroll
        for (int i = 0; i < 16; ++i) Uws[r * 256 + j * 16 + i] = st[i];
    } else {
        _Float16* Wh = (_Float16*)ws;
        #pragma unroll
        for (int t = 0; t < 8; ++t) {
            int f  = tid * 8 + t;            // fragment id 0..2047
            int cg = f >> 9;
            int kk = (f >> 6) & 7;
            int l  = f & 63;
            int row = cg * 16 + (l & 15);
            int k0  = (kk * 4 + (l >> 4)) * 8;
            const float* src = W + row * 256 + k0;
            f16x8 h;
            #pragma unroll
            for (int e = 0; e < 8; ++e) h[e] = (_Float16)src[e];
            *(f16x8*)(Wh + f * 8) = h;
        }
    }
}

// Stage a 64x256 fp32 tile as fp16 into LDS with 16B-slot XOR swizzle.
// byte addr = row*512 + ((slot ^ (row&7))*16 + (k&7)*2), slot = k>>3.
__device__ __forceinline__ void stage_tile(const float* __restrict__ src,
                                           char* dst, int tid) {
    const float4* s4 = (const float4*)src;
    #pragma unroll
    for (int it = 0; it < 16; ++it) {
        int q = tid + it * 256;            // float4 index, 4096 total
        float4 v = s4[q];
        int row = q >> 6;
        int c4  = (q & 63) << 2;
        int sl  = (c4 >> 3) ^ (row & 7);
        int byteoff = row * 512 + (sl << 4) + ((c4 & 7) << 1);
        f16x4 h = { (_Float16)v.x, (_Float16)v.y, (_Float16)v.z, (_Float16)v.w };
        *(f16x4*)(dst + byteoff) = h;
    }
}

__global__ __launch_bounds__(256) void vqc_main_kernel(
        const float* __restrict__ fused,   // (65536, 256)
        const char* __restrict__ ws,       // Wh fp16 frags + U fp32
        const float* __restrict__ bp,      // (64,)
        float* __restrict__ out) {         // (65536, 64)
    __shared__ __align__(16) char smem[32768];

    const int tid = threadIdx.x;
    const int b0  = blockIdx.x * 64;

    stage_tile(fused + (size_t)b0 * 256, smem, tid);
    __syncthreads();

    const int lane = tid & 63;
    const int wv   = tid >> 6;
    const int l15  = lane & 15;
    const int l4   = lane >> 4;
    const int frow = wv * 16 + l15;        // sample row (B operand)

    const f16x8* Wf = (const f16x8*)ws;    // fragment-ordered fp16 W

    // ---- MFMA: D = W-rows (A) x fused-rows (B) -> pre^T fragments ----
    f32x4 acc[4] = {};
    #pragma unroll
    for (int kk = 0; kk < 8; ++kk) {
        int slot = kk * 4 + l4;
        f16x8 bf = *(const f16x8*)(smem + frow * 512 + ((slot ^ (frow & 7)) << 4));
        #pragma unroll
        for (int cg = 0; cg < 4; ++cg) {
            f16x8 af = Wf[(cg * 8 + kk) * 64 + lane];
            acc[cg] = __builtin_amdgcn_mfma_f32_16x16x32_f16(af, bf, acc[cg], 0, 0, 0);
        }
    }
    __syncthreads();                       // A-tile dead; reuse as park buffer

    // ---- park pre^T: acc[cg][j] = pre[frow][angle = 16cg+4*l4+j] ----
    float* Cp = (float*)smem;              // [64 angles][66] fp32
    #pragma unroll
    for (int cg = 0; cg < 4; ++cg) {
        #pragma unroll
        for (int j = 0; j < 4; ++j) {
            Cp[(16 * cg + 4 * l4 + j) * 66 + frow] = acc[cg][j];
        }
    }
    __syncthreads();

    // ---- circuit epilogue: wave wv owns runs 4wv..4wv+3 (wave-uniform) ----
    #pragma unroll 1
    for (int c = 0; c < 4; ++c) {
        const int r = __builtin_amdgcn_readfirstlane((tid >> 6) * 4 + c);
        const float* Ur = (const float*)(ws + 32768) + (r << 8);  // uniform
        float4 bias = *(const float4*)(bp + 4 * r);               // uniform

        float pre[4];
        #pragma unroll
        for (int j = 0; j < 4; ++j)
            pre[j] = Cp[(4 * r + j) * 66 + lane];
        pre[0] += bias.x; pre[1] += bias.y; pre[2] += bias.z; pre[3] += bias.w;

        float cc[4], ss[4];
        #pragma unroll
        for (int w = 0; w < 4; ++w) {
            float e  = __expf(2.f * pre[w]);
            float th = __fdividef(e - 1.f, e + 1.f);   // tanh(pre)
            float h  = th * (0.5f * PI_F);             // theta/2
            __sincosf(h, &ss[w], &cc[w]);
        }

        // s_enc = a01 (x) a23
        float a01[4] = {cc[0]*cc[1], cc[0]*ss[1], ss[0]*cc[1], ss[0]*ss[1]};
        float a23[4] = {cc[2]*cc[3], cc[2]*ss[3], ss[2]*cc[3], ss[2]*ss[3]};
        float se[16];
        #pragma unroll
        for (int hi = 0; hi < 4; ++hi)
            #pragma unroll
            for (int lo = 0; lo < 4; ++lo)
                se[hi * 4 + lo] = a01[hi] * a23[lo];

        // o = U_r * s_enc   (U rows from scalar loads; 256 FMA)
        float o[16];
        #pragma unroll
        for (int i = 0; i < 16; ++i) o[i] = 0.f;
        #pragma unroll
        for (int j = 0; j < 16; ++j) {
            float sj = se[j];
            const float4* up = (const float4*)(Ur + j * 16);
            #pragma unroll
            for (int q = 0; q < 4; ++q) {
                float4 u = up[q];
                o[4*q+0] = fmaf(u.x, sj, o[4*q+0]);
                o[4*q+1] = fmaf(u.y, sj, o[4*q+1]);
                o[4*q+2] = fmaf(u.z, sj, o[4*q+2]);
                o[4*q+3] = fmaf(u.w, sj, o[4*q+3]);
            }
        }

        // z-reduction (tree)
        float p[16];
        #pragma unroll
        for (int i = 0; i < 16; ++i) p[i] = o[i] * o[i];
        float s01[8], d01[8];
        #pragma unroll
        for (int k = 0; k < 8; ++k) {
            s01[k] = p[2*k] + p[2*k+1];
            d01[k] = p[2*k] - p[2*k+1];
        }
        float z3 = ((d01[0]+d01[1])+(d01[2]+d01[3]))+((d01[4]+d01[5])+(d01[6]+d01[7]));
        float z2 = ((s01[0]-s01[1])+(s01[2]-s01[3]))+((s01[4]-s01[5])+(s01[6]-s01[7]));
        float t0 = s01[0]+s01[1], t1 = s01[2]+s01[3], t2 = s01[4]+s01[5], t3 = s01[6]+s01[7];
        float z1 = (t0 - t1) + (t2 - t3);
        float z0 = (t0 + t1) - (t2 + t3);

        float4 ov;
        ov.x = (z0 + 1.f) * PI_F;
        ov.y = (z1 + 1.f) * PI_F;
        ov.z = (z2 + 1.f) * PI_F;
        ov.w = (z3 + 1.f) * PI_F;
        *(float4*)(out + (size_t)(b0 + lane) * 64 + 4 * r) = ov;
    }
}

extern "C" void kernel_launch(void* const* d_in, const int* in_sizes, int n_in,
                              void* d_out, int out_size, void* d_ws, size_t ws_size,
                              hipStream_t stream) {
    const float* fused = (const float*)d_in[0];   // (65536, 256)
    const float* Wp    = (const float*)d_in[1];   // (64, 256)
    const float* bp    = (const float*)d_in[2];   // (64,)
    const float* vw    = (const float*)d_in[3];   // (16, 4, 4)
    float* out = (float*)d_out;                   // (65536, 64)
    char*  ws  = (char*)d_ws;                     // 48 KB used

    prep_kernel<<<2, 256, 0, stream>>>(vw, Wp, ws);

    const int B = 65536;
    vqc_main_kernel<<<B / 64, 256, 0, stream>>>(fused, ws, bp, out);
}